// Round 11
// baseline (199.922 us; speedup 1.0000x reference)
//
#include <hip/hip_runtime.h>
#include <hip/hip_bf16.h>
#include <math.h>

#define N_NODES 50000
#define N_EDGES 625000
#define HID 128
#define N_GRAPHS 1000
#define N_FEATS 9
#define VOCAB 119
#define SENTINEL N_NODES    // gathers of pad slots hit this all-zero row
#define CAP 64              // per-node LDS list capacity (max Poisson(12.5) deg ~40)
#define NBIN (N_NODES / 16) // 3125 bins of 16 consecutive nodes
#define CAPB 320            // bin capacity (Poisson(200) max ~278)
#define NB_SCAN ((N_NODES + 255) / 256)
#define LDSW 136            // 128 + 8 pad shorts: 16B-aligned, breaks bank conflicts

// fat fillprep_k block ranges
#define FB ((N_EDGES + 255) / 256)             // 2442 fill blocks
#define PB ((32897 + N_NODES + 1 + 255) / 256) // 325 prep blocks

typedef __attribute__((ext_vector_type(8))) short short8;
typedef __attribute__((ext_vector_type(8))) unsigned short ushort8;
typedef __attribute__((ext_vector_type(4))) float f32x4;

// ---- bf16 helpers ----
static __device__ __forceinline__ float bflo(unsigned int w) {
    return __uint_as_float(w << 16);
}
static __device__ __forceinline__ float bfhi(unsigned int w) {
    return __uint_as_float(w & 0xffff0000u);
}
static __device__ __forceinline__ unsigned int f2bf(float f) {
    unsigned int u = __float_as_uint(f);
    return (u + 0x7fffu + ((u >> 16) & 1u)) >> 16;   // RNE
}
static __device__ __forceinline__ uint2 pack4(float a, float b, float c, float d) {
    uint2 r;
    r.x = f2bf(a) | (f2bf(b) << 16);
    r.y = f2bf(c) | (f2bf(d) << 16);
    return r;
}

// ---------------- init: zero deg/bincur/gacc + sentinel rows + sp sentinel ----------------
__global__ __launch_bounds__(256) void init_k(int* __restrict__ deg,
                                              int* __restrict__ bincur,
                                              float* __restrict__ gacc,
                                              unsigned int* __restrict__ hpA_sent,
                                              unsigned int* __restrict__ hpB_sent,
                                              float* __restrict__ sp) {
    int i = blockIdx.x * 256 + threadIdx.x;
    if (i < N_NODES) deg[i] = 0;
    if (i < NBIN) bincur[i] = 0;
    if (i < N_GRAPHS) gacc[i] = 0.f;
    if (i < 64) { hpA_sent[i] = 0; hpB_sent[i] = 0; }   // row 50000: 128 bf16 = 64 u32
    if (i == 64) sp[SENTINEL] = 0.f;
}

// ---------------- fat kernel: bin fill (+degree count) | weight prep ----------------
__global__ __launch_bounds__(256) void fillprep_k(const int* __restrict__ row,
                                                  const int* __restrict__ col,
                                                  int* __restrict__ deg,
                                                  int* __restrict__ bincur,
                                                  unsigned int* __restrict__ binbuf,
                                                  const float* __restrict__ W1,
                                                  const float* __restrict__ W2,
                                                  const float* __restrict__ W3,
                                                  const float* __restrict__ b3,
                                                  const float* __restrict__ lw,
                                                  const int* __restrict__ batch,
                                                  unsigned short* __restrict__ Wt,
                                                  float* __restrict__ wtil,
                                                  float* __restrict__ cbuf,
                                                  int* __restrict__ goff) {
    int b = blockIdx.x;
    if (b < FB) {
        // ---- bin fill: dense appends per 16-node bin + degree count ----
        int e = b * 256 + threadIdx.x;
        if (e >= N_EDGES) return;
        int c = col[e];
        int r = row[e];
        atomicAdd(&deg[c], 1);
        int bin = c >> 4;
        int pos = atomicAdd(&bincur[bin], 1);
        if (pos < CAPB)
            binbuf[bin * CAPB + pos] = ((unsigned int)r << 4) | (unsigned int)(c & 15);
    } else {
        // ---- prep: Wt transpose, w~ = W3@lin_w, cb3 = b3.lin_w, goff ----
        int t = (b - FB) * 256 + threadIdx.x;
        if (t < 32768) {
            int which = t >> 14;
            int rem = t & 16383;
            int n = rem >> 7, k = rem & 127;
            const float* W = which ? W2 : W1;
            Wt[which * 16384 + n * 128 + k] = (unsigned short)f2bf(W[k * 128 + n]);
        } else if (t < 32896) {
            int k = t - 32768;
            float s = 0.f;
            for (int n = 0; n < 128; n++) s += W3[k * 128 + n] * lw[n];
            wtil[k] = s;
        } else if (t == 32896) {
            float s = 0.f;
            for (int n = 0; n < 128; n++) s += b3[n] * lw[n];
            cbuf[0] = s;
        } else {
            int i = t - 32897;
            if (i > N_NODES) return;
            int bprev = (i == 0) ? -1 : batch[i - 1];
            int bcur = (i == N_NODES) ? N_GRAPHS : batch[i];
            for (int g = bprev + 1; g <= bcur; g++) goff[g] = i;
        }
    }
}

// ---------------- atom encoder: dinv inline from deg, prescaled bf16 hp0 ----------------
__global__ __launch_bounds__(256) void atom_k(const int* __restrict__ x,
                                              const float* __restrict__ emb,
                                              const int* __restrict__ deg,
                                              float* __restrict__ dinv,
                                              unsigned short* __restrict__ hp) {
    int gid = blockIdx.x * 256 + threadIdx.x;   // N*32 threads
    int node = gid >> 5;
    int sub = gid & 31;
    if (node >= N_NODES) return;
    float di = rsqrtf((float)(deg[node] + 1));  // +1 self loop
    if (sub == 0) dinv[node] = di;
    int d4 = sub * 4;
    float4 acc = make_float4(0.f, 0.f, 0.f, 0.f);
#pragma unroll
    for (int f = 0; f < N_FEATS; f++) {
        int idx = x[node * N_FEATS + f];
        const float4 v = *(const float4*)(emb + ((size_t)(f * VOCAB + idx)) * HID + d4);
        acc.x += v.x; acc.y += v.y; acc.z += v.z; acc.w += v.w;
    }
    ((uint2*)hp)[(size_t)node * 32 + sub] =
        pack4(di * acc.x, di * acc.y, di * acc.z, di * acc.w);
}

// ---- LDS list staging: bin records -> 16 per-node lists, %8-padded with SENTINEL ----
// lists: [16][CAP] ushort, lcnt[16] = padded length. Call with all 256 threads.
#define STAGE_LISTS(binbuf_, bincur_)                                           \
    if (threadIdx.x < 16) lcur[threadIdx.x] = 0;                                \
    __syncthreads();                                                            \
    {                                                                           \
        int nrec = bincur_[blockIdx.x];                                         \
        if (nrec > CAPB) nrec = CAPB;                                           \
        const unsigned int* bb = binbuf_ + (size_t)blockIdx.x * CAPB;           \
        for (int i = threadIdx.x; i < nrec; i += 256) {                         \
            unsigned int rec = bb[i];                                           \
            int nl2 = rec & 15;                                                 \
            int p = atomicAdd(&lcur[nl2], 1);                                   \
            if (p < CAP) lists[nl2][p] = (unsigned short)(rec >> 4);            \
        }                                                                       \
    }                                                                           \
    __syncthreads();                                                            \
    if (threadIdx.x < 16) {                                                     \
        int d = lcur[threadIdx.x]; if (d > CAP) d = CAP;                        \
        int e8 = (d + 7) & ~7; if (e8 > CAP) e8 = CAP;                          \
        for (int j = d; j < e8; j++) lists[threadIdx.x][j] = (unsigned short)SENTINEL; \
        lcnt[threadIdx.x] = e8;                                                 \
    }                                                                           \
    __syncthreads();

// ---------------- fused layer: block = bin (16 nodes); LDS lists -> gather -> MFMA ----------------
template <int DOT>
__global__ __launch_bounds__(256) void fused_k(const unsigned short* __restrict__ hp_in,
                                               const unsigned int* __restrict__ binbuf,
                                               const int* __restrict__ bincur,
                                               const unsigned short* __restrict__ Wt,
                                               const float* __restrict__ bias,
                                               const float* __restrict__ dinv,
                                               unsigned short* __restrict__ hp_out,
                                               const float* __restrict__ wtil,
                                               float* __restrict__ sp) {
    __shared__ unsigned short a_sh[16 * LDSW];
    __shared__ float spart[64];
    __shared__ unsigned short lists[16][CAP];
    __shared__ int lcur[16];
    __shared__ int lcnt[16];
    int tid = threadIdx.x;
    STAGE_LISTS(binbuf, bincur)
    int sub = tid & 15, nl = tid >> 4;          // nl = node_local 0..15
    int node = blockIdx.x * 16 + nl;            // always < N_NODES
    const uint4* H = (const uint4*)hp_in;
    {
        int e = lcnt[nl];
        uint4 v = H[(size_t)node * 16 + sub];   // self (prescaled)
        float a0 = bflo(v.x), a1 = bfhi(v.x), a2 = bflo(v.y), a3 = bfhi(v.y);
        float a4 = bflo(v.z), a5 = bfhi(v.z), a6 = bflo(v.w), a7 = bfhi(v.w);
        for (int i = 0; i < e; i += 8) {
            ushort8 r = *(const ushort8*)&lists[nl][i];   // LDS broadcast, 16B
            uint4 u0 = H[(size_t)r[0] * 16 + sub];
            uint4 u1 = H[(size_t)r[1] * 16 + sub];
            uint4 u2 = H[(size_t)r[2] * 16 + sub];
            uint4 u3 = H[(size_t)r[3] * 16 + sub];
            uint4 u4 = H[(size_t)r[4] * 16 + sub];
            uint4 u5 = H[(size_t)r[5] * 16 + sub];
            uint4 u6 = H[(size_t)r[6] * 16 + sub];
            uint4 u7 = H[(size_t)r[7] * 16 + sub];
            a0 += bflo(u0.x); a1 += bfhi(u0.x); a2 += bflo(u0.y); a3 += bfhi(u0.y);
            a4 += bflo(u0.z); a5 += bfhi(u0.z); a6 += bflo(u0.w); a7 += bfhi(u0.w);
            a0 += bflo(u1.x); a1 += bfhi(u1.x); a2 += bflo(u1.y); a3 += bfhi(u1.y);
            a4 += bflo(u1.z); a5 += bfhi(u1.z); a6 += bflo(u1.w); a7 += bfhi(u1.w);
            a0 += bflo(u2.x); a1 += bfhi(u2.x); a2 += bflo(u2.y); a3 += bfhi(u2.y);
            a4 += bflo(u2.z); a5 += bfhi(u2.z); a6 += bflo(u2.w); a7 += bfhi(u2.w);
            a0 += bflo(u3.x); a1 += bfhi(u3.x); a2 += bflo(u3.y); a3 += bfhi(u3.y);
            a4 += bflo(u3.z); a5 += bfhi(u3.z); a6 += bflo(u3.w); a7 += bfhi(u3.w);
            a0 += bflo(u4.x); a1 += bfhi(u4.x); a2 += bflo(u4.y); a3 += bfhi(u4.y);
            a4 += bflo(u4.z); a5 += bfhi(u4.z); a6 += bflo(u4.w); a7 += bfhi(u4.w);
            a0 += bflo(u5.x); a1 += bfhi(u5.x); a2 += bflo(u5.y); a3 += bfhi(u5.y);
            a4 += bflo(u5.z); a5 += bfhi(u5.z); a6 += bflo(u5.w); a7 += bfhi(u5.w);
            a0 += bflo(u6.x); a1 += bfhi(u6.x); a2 += bflo(u6.y); a3 += bfhi(u6.y);
            a4 += bflo(u6.z); a5 += bfhi(u6.z); a6 += bflo(u6.w); a7 += bfhi(u6.w);
            a0 += bflo(u7.x); a1 += bfhi(u7.x); a2 += bflo(u7.y); a3 += bfhi(u7.y);
            a4 += bflo(u7.z); a5 += bfhi(u7.z); a6 += bflo(u7.w); a7 += bfhi(u7.w);
        }
        float di = dinv[node];                  // (A^ h)_i = di * (sum + self)
        uint2 p0 = pack4(di * a0, di * a1, di * a2, di * a3);
        uint2 p1 = pack4(di * a4, di * a5, di * a6, di * a7);
        uint4 o; o.x = p0.x; o.y = p0.y; o.z = p1.x; o.w = p1.y;
        *(uint4*)(a_sh + nl * LDSW + sub * 8) = o;
    }
    __syncthreads();
    // MFMA phase: wave w -> cols w*32..+31, rows 0..15
    int w = tid >> 6, l = tid & 63;
    int lm = l & 15, lk = l >> 4;
    int cbase = w * 32;
    f32x4 acc[2];
    acc[0] = (f32x4)0.f; acc[1] = (f32x4)0.f;
#pragma unroll
    for (int kk = 0; kk < 4; kk++) {
        short8 af = *(const short8*)(a_sh + lm * LDSW + (kk * 4 + lk) * 8);
#pragma unroll
        for (int nt = 0; nt < 2; nt++) {
            short8 bf = *(const short8*)(Wt + (size_t)(cbase + nt * 16 + lm) * HID + (kk * 4 + lk) * 8);
            acc[nt] = __builtin_amdgcn_mfma_f32_16x16x32_bf16(bf, af, acc[nt], 0, 0, 0);
        }
    }
    int m = blockIdx.x * 16 + lm;
    float di = dinv[m];
    if (DOT == 0) {
#pragma unroll
        for (int nt = 0; nt < 2; nt++) {
            int n0 = cbase + nt * 16 + lk * 4;
            float4 b4 = *(const float4*)(bias + n0);
            float o0 = di * fmaxf(acc[nt][0] + b4.x, 0.f);
            float o1 = di * fmaxf(acc[nt][1] + b4.y, 0.f);
            float o2 = di * fmaxf(acc[nt][2] + b4.z, 0.f);
            float o3 = di * fmaxf(acc[nt][3] + b4.w, 0.f);
            *(uint2*)(hp_out + (size_t)m * HID + n0) = pack4(o0, o1, o2, o3);
        }
    } else {
        float s = 0.f;
#pragma unroll
        for (int nt = 0; nt < 2; nt++) {
            int n0 = cbase + nt * 16 + lk * 4;
            float4 b4 = *(const float4*)(bias + n0);
            float4 w4 = *(const float4*)(wtil + n0);
            s += di * fmaxf(acc[nt][0] + b4.x, 0.f) * w4.x
               + di * fmaxf(acc[nt][1] + b4.y, 0.f) * w4.y
               + di * fmaxf(acc[nt][2] + b4.z, 0.f) * w4.z
               + di * fmaxf(acc[nt][3] + b4.w, 0.f) * w4.w;
        }
        s += __shfl_xor(s, 16, 64);
        s += __shfl_xor(s, 32, 64);             // lanes with lk==0 hold row sum of 32 cols
        if (lk == 0) spart[w * 16 + lm] = s;
        __syncthreads();
        if (tid < 16)
            sp[blockIdx.x * 16 + tid] =
                spart[tid] + spart[16 + tid] + spart[32 + tid] + spart[48 + tid];
    }
}

// ---------------- head part 1: per-bin scalar layer-3 agg -> atomic per-graph sum ----------------
__global__ __launch_bounds__(256) void gout_k(const float* __restrict__ sp,
                                              const unsigned int* __restrict__ binbuf,
                                              const int* __restrict__ bincur,
                                              const float* __restrict__ dinv,
                                              const int* __restrict__ batch,
                                              float* __restrict__ gacc) {
    __shared__ unsigned short lists[16][CAP];
    __shared__ int lcur[16];
    __shared__ int lcnt[16];
    STAGE_LISTS(binbuf, bincur)
    int nl = threadIdx.x >> 4, lane = threadIdx.x & 15;
    int node = blockIdx.x * 16 + nl;
    int e = lcnt[nl];
    float s = 0.f;
    for (int i = lane; i < e; i += 16) s += sp[lists[nl][i]];
#pragma unroll
    for (int o = 8; o >= 1; o >>= 1) s += __shfl_xor(s, o, 64);  // within 16-lane group
    if (lane == 0) {
        float t = dinv[node] * (sp[node] + s);
        atomicAdd(&gacc[batch[node]], t);
    }
}

// ---------------- head part 2: mean + sigmoid ----------------
__global__ __launch_bounds__(1024) void final_k(const float* __restrict__ gacc,
                                                const int* __restrict__ goff,
                                                const float* __restrict__ cbuf,
                                                const float* __restrict__ lin_b,
                                                float* __restrict__ out) {
    int g = threadIdx.x;
    if (g >= N_GRAPHS) return;
    int cnt = goff[g + 1] - goff[g];
    float z = (cnt == 0) ? lin_b[0]
                         : (gacc[g] / (float)cnt + cbuf[0] + lin_b[0]);
    out[g] = 1.0f / (1.0f + expf(-z));
}

extern "C" void kernel_launch(void* const* d_in, const int* in_sizes, int n_in,
                              void* d_out, int out_size, void* d_ws, size_t ws_size,
                              hipStream_t stream) {
    const int* x      = (const int*)d_in[0];
    const int* ei     = (const int*)d_in[1];
    const int* batch  = (const int*)d_in[2];
    const float* emb  = (const float*)d_in[3];
    const float* W1   = (const float*)d_in[4];
    const float* b1   = (const float*)d_in[5];
    const float* W2   = (const float*)d_in[6];
    const float* b2   = (const float*)d_in[7];
    const float* W3   = (const float*)d_in[8];
    const float* b3   = (const float*)d_in[9];
    const float* lw   = (const float*)d_in[10];
    const float* lb   = (const float*)d_in[11];
    float* out = (float*)d_out;

    char* ws = (char*)d_ws;
    size_t off = 0;
    auto alloc = [&](size_t bytes) {
        void* p = ws + off;
        off = (off + bytes + 255) & ~(size_t)255;
        return p;
    };
    int*   deg     = (int*)alloc((size_t)N_NODES * 4);
    int*   bincur  = (int*)alloc((size_t)NBIN * 4);
    float* dinv    = (float*)alloc((size_t)N_NODES * 4);
    unsigned int* binbuf = (unsigned int*)alloc((size_t)NBIN * CAPB * 4);
    unsigned short* hpA  = (unsigned short*)alloc((size_t)(N_NODES + 1) * HID * 2);
    unsigned short* hpB  = (unsigned short*)alloc((size_t)(N_NODES + 1) * HID * 2);
    unsigned short* Wt   = (unsigned short*)alloc((size_t)2 * HID * HID * 2);
    float* wtil    = (float*)alloc((size_t)HID * 4);
    float* cbuf    = (float*)alloc(256);
    float* sp      = (float*)alloc((size_t)(N_NODES + 1) * 4);
    int*   goff    = (int*)alloc((size_t)(N_GRAPHS + 1) * 4);
    float* gacc    = (float*)alloc((size_t)N_GRAPHS * 4);

    const int* row = ei;
    const int* col = ei + N_EDGES;

    init_k<<<NB_SCAN, 256, 0, stream>>>(deg, bincur, gacc,
                                        (unsigned int*)(hpA + (size_t)SENTINEL * HID),
                                        (unsigned int*)(hpB + (size_t)SENTINEL * HID),
                                        sp);
    // bin fill (dense appends) + degree count | weight prep  — one fat kernel
    fillprep_k<<<FB + PB, 256, 0, stream>>>(row, col, deg, bincur, binbuf,
                                            W1, W2, W3, b3, lw, batch,
                                            Wt, wtil, cbuf, goff);
    // atom encoder (dinv inline from deg)
    atom_k<<<(N_NODES * 32) / 256, 256, 0, stream>>>(x, emb, deg, dinv, hpA);

    // layer 1: stage lists + gather + MFMA -> hpB
    fused_k<0><<<NBIN, 256, 0, stream>>>(hpA, binbuf, bincur, Wt, b1, dinv, hpB, wtil, sp);
    // layer 2: stage lists + gather + MFMA + dot(w~) -> sp
    fused_k<1><<<NBIN, 256, 0, stream>>>(hpB, binbuf, bincur, Wt + 16384, b2, dinv, hpA, wtil, sp);

    // head: per-bin scalar layer-3 agg -> per-graph atomic sum -> sigmoid
    gout_k<<<NBIN, 256, 0, stream>>>(sp, binbuf, bincur, dinv, batch, gacc);
    final_k<<<1, 1024, 0, stream>>>(gacc, goff, cbuf, lb, out);
}

// Round 12
// 126.814 us; speedup vs baseline: 1.5765x; 1.5765x over previous
//
#include <hip/hip_runtime.h>
#include <hip/hip_bf16.h>
#include <math.h>

#define N_NODES 50000
#define N_EDGES 625000
#define HID 128
#define N_GRAPHS 1000
#define N_FEATS 9
#define VOCAB 119
#define SENTINEL N_NODES    // gathers of pad slots hit this all-zero row
#define CAP 64              // per-node bucket capacity (max Poisson(12.5) deg ~40)
#define CAPLOG 6
#define NPART 8             // XCD count: node-partitioned fill for write ownership
#define PARTSZ (N_NODES / NPART)   // 6250
#define NB_SCAN ((N_NODES + 255) / 256)
#define LDSW 136            // 128 + 8 pad shorts: 16B-aligned, breaks bank conflicts
#define NBLK (N_NODES / 16) // 3125 fused blocks, exact

// fat mid_k block ranges
#define FSLICE ((N_EDGES + 255) / 256)         // 2442 edge slices
#define FB (FSLICE * NPART)                    // 19536 fill blocks (8 per slice)
#define PB ((32897 + N_NODES + 1 + 255) / 256) // 325 prep blocks

typedef __attribute__((ext_vector_type(8))) short short8;
typedef __attribute__((ext_vector_type(8))) unsigned short ushort8;
typedef __attribute__((ext_vector_type(4))) float f32x4;

// ---- bf16 helpers ----
static __device__ __forceinline__ float bflo(unsigned int w) {
    return __uint_as_float(w << 16);
}
static __device__ __forceinline__ float bfhi(unsigned int w) {
    return __uint_as_float(w & 0xffff0000u);
}
static __device__ __forceinline__ unsigned int f2bf(float f) {
    unsigned int u = __float_as_uint(f);
    return (u + 0x7fffu + ((u >> 16) & 1u)) >> 16;   // RNE
}
static __device__ __forceinline__ uint2 pack4(float a, float b, float c, float d) {
    uint2 r;
    r.x = f2bf(a) | (f2bf(b) << 16);
    r.y = f2bf(c) | (f2bf(d) << 16);
    return r;
}

// ---------------- init: zero cursor + sentinel rows + sp sentinel ----------------
__global__ __launch_bounds__(256) void init_k(int* __restrict__ cursor,
                                              unsigned int* __restrict__ hpA_sent,
                                              unsigned int* __restrict__ hpB_sent,
                                              float* __restrict__ sp) {
    int i = blockIdx.x * 256 + threadIdx.x;
    if (i < N_NODES) cursor[i] = 0;
    if (i < 64) { hpA_sent[i] = 0; hpB_sent[i] = 0; }   // row 50000: 128 bf16 = 64 u32
    if (i == 64) sp[SENTINEL] = 0.f;
}

// ---------------- fat kernel: partition-affine bucket fill | weight prep ----------------
// Fill: 8 blocks per edge slice; block 8s+p writes only cols in partition p.
// Under round-robin block->XCD placement, each csrc/cursor line is written by ONE
// XCD only -> no cross-XCD line bouncing. Correct under any placement.
// After this kernel, cursor[i] == degree(i)  (count_k deleted).
__global__ __launch_bounds__(256) void mid_k(const int* __restrict__ row,
                                             const int* __restrict__ col,
                                             int* __restrict__ cursor,
                                             unsigned short* __restrict__ csrc,
                                             const float* __restrict__ W1,
                                             const float* __restrict__ W2,
                                             const float* __restrict__ W3,
                                             const float* __restrict__ b3,
                                             const float* __restrict__ lw,
                                             const int* __restrict__ batch,
                                             unsigned short* __restrict__ Wt,
                                             float* __restrict__ wtil,
                                             float* __restrict__ cbuf,
                                             int* __restrict__ goff) {
    int b = blockIdx.x;
    if (b < FB) {
        int slice = b >> 3;
        int part = b & 7;
        int e = slice * 256 + threadIdx.x;
        if (e >= N_EDGES) return;
        int c = col[e];
        if ((unsigned)(c - part * PARTSZ) < (unsigned)PARTSZ) {
            int pos = atomicAdd(&cursor[c], 1);
            if (pos < CAP)
                csrc[((size_t)c << CAPLOG) + pos] = (unsigned short)row[e];
        }
    } else {
        // ---- prep: Wt transpose, w~ = W3@lin_w, cb3 = b3.lin_w, goff ----
        int t = (b - FB) * 256 + threadIdx.x;
        if (t < 32768) {
            int which = t >> 14;
            int rem = t & 16383;
            int n = rem >> 7, k = rem & 127;
            const float* W = which ? W2 : W1;
            Wt[which * 16384 + n * 128 + k] = (unsigned short)f2bf(W[k * 128 + n]);
        } else if (t < 32896) {
            int k = t - 32768;
            float s = 0.f;
            for (int n = 0; n < 128; n++) s += W3[k * 128 + n] * lw[n];
            wtil[k] = s;
        } else if (t == 32896) {
            float s = 0.f;
            for (int n = 0; n < 128; n++) s += b3[n] * lw[n];
            cbuf[0] = s;
        } else {
            int i = t - 32897;
            if (i > N_NODES) return;
            int bprev = (i == 0) ? -1 : batch[i - 1];
            int bcur = (i == N_NODES) ? N_GRAPHS : batch[i];
            for (int g = bprev + 1; g <= bcur; g++) goff[g] = i;
        }
    }
}

// ------- atom encoder + dinv from cursor(==deg) + bucket sentinel padding -------
__global__ __launch_bounds__(256) void atomdinv_k(const int* __restrict__ x,
                                                  const float* __restrict__ emb,
                                                  const int* __restrict__ cursor,
                                                  float* __restrict__ dinv,
                                                  unsigned short* __restrict__ csrc,
                                                  unsigned short* __restrict__ hp) {
    int gid = blockIdx.x * 256 + threadIdx.x;   // N*32 threads
    int node = gid >> 5;
    int sub = gid & 31;
    if (node >= N_NODES) return;
    int d = cursor[node];                       // true degree
    float di = rsqrtf((float)(d + 1));          // +1 self loop
    if (sub == 0) {
        dinv[node] = di;
        if (d > CAP) d = CAP;
        int r8 = (d + 7) & ~7;
        if (r8 > CAP) r8 = CAP;
        unsigned short* bk = csrc + ((size_t)node << CAPLOG);
        for (int j = d; j < r8; j++) bk[j] = (unsigned short)SENTINEL;
    }
    int d4 = sub * 4;
    float4 acc = make_float4(0.f, 0.f, 0.f, 0.f);
#pragma unroll
    for (int f = 0; f < N_FEATS; f++) {
        int idx = x[node * N_FEATS + f];
        const float4 v = *(const float4*)(emb + ((size_t)(f * VOCAB + idx)) * HID + d4);
        acc.x += v.x; acc.y += v.y; acc.z += v.z; acc.w += v.w;
    }
    ((uint2*)hp)[(size_t)node * 32 + sub] =
        pack4(di * acc.x, di * acc.y, di * acc.z, di * acc.w);
}

// ---------------- fused layer: 16 nodes/block, one node per 16-lane group ----------------
// Gather: 8 edges per iteration (one 16B ushort8 index load -> 8 in-flight 256B row gathers).
template <int DOT>
__global__ __launch_bounds__(256) void fused_k(const unsigned short* __restrict__ hp_in,
                                               const unsigned short* __restrict__ Wt,
                                               const float* __restrict__ bias,
                                               const float* __restrict__ dinv,
                                               const int* __restrict__ deg,
                                               const unsigned short* __restrict__ csrc,
                                               unsigned short* __restrict__ hp_out,
                                               const float* __restrict__ wtil,
                                               float* __restrict__ sp) {
    __shared__ unsigned short a_sh[16 * LDSW];
    __shared__ float spart[64];
    int tid = threadIdx.x;
    int sub = tid & 15, nl = tid >> 4;          // nl = node_local 0..15
    int node = blockIdx.x * 16 + nl;            // always < N_NODES (50000 = 16*3125)
    const uint4* H = (const uint4*)hp_in;
    {
        int d = deg[node];
        if (d > CAP) d = CAP;
        int e = (d + 7) & ~7;
        if (e > CAP) e = CAP;
        const unsigned short* bk = csrc + ((size_t)node << CAPLOG);
        uint4 v = H[(size_t)node * 16 + sub];   // self (prescaled)
        float a0 = bflo(v.x), a1 = bfhi(v.x), a2 = bflo(v.y), a3 = bfhi(v.y);
        float a4 = bflo(v.z), a5 = bfhi(v.z), a6 = bflo(v.w), a7 = bfhi(v.w);
        for (int i = 0; i < e; i += 8) {
            ushort8 r = *(const ushort8*)(bk + i);     // 16B-aligned index load
            uint4 u0 = H[(size_t)r[0] * 16 + sub];
            uint4 u1 = H[(size_t)r[1] * 16 + sub];
            uint4 u2 = H[(size_t)r[2] * 16 + sub];
            uint4 u3 = H[(size_t)r[3] * 16 + sub];
            uint4 u4 = H[(size_t)r[4] * 16 + sub];
            uint4 u5 = H[(size_t)r[5] * 16 + sub];
            uint4 u6 = H[(size_t)r[6] * 16 + sub];
            uint4 u7 = H[(size_t)r[7] * 16 + sub];
            a0 += bflo(u0.x); a1 += bfhi(u0.x); a2 += bflo(u0.y); a3 += bfhi(u0.y);
            a4 += bflo(u0.z); a5 += bfhi(u0.z); a6 += bflo(u0.w); a7 += bfhi(u0.w);
            a0 += bflo(u1.x); a1 += bfhi(u1.x); a2 += bflo(u1.y); a3 += bfhi(u1.y);
            a4 += bflo(u1.z); a5 += bfhi(u1.z); a6 += bflo(u1.w); a7 += bfhi(u1.w);
            a0 += bflo(u2.x); a1 += bfhi(u2.x); a2 += bflo(u2.y); a3 += bfhi(u2.y);
            a4 += bflo(u2.z); a5 += bfhi(u2.z); a6 += bflo(u2.w); a7 += bfhi(u2.w);
            a0 += bflo(u3.x); a1 += bfhi(u3.x); a2 += bflo(u3.y); a3 += bfhi(u3.y);
            a4 += bflo(u3.z); a5 += bfhi(u3.z); a6 += bflo(u3.w); a7 += bfhi(u3.w);
            a0 += bflo(u4.x); a1 += bfhi(u4.x); a2 += bflo(u4.y); a3 += bfhi(u4.y);
            a4 += bflo(u4.z); a5 += bfhi(u4.z); a6 += bflo(u4.w); a7 += bfhi(u4.w);
            a0 += bflo(u5.x); a1 += bfhi(u5.x); a2 += bflo(u5.y); a3 += bfhi(u5.y);
            a4 += bflo(u5.z); a5 += bfhi(u5.z); a6 += bflo(u5.w); a7 += bfhi(u5.w);
            a0 += bflo(u6.x); a1 += bfhi(u6.x); a2 += bflo(u6.y); a3 += bfhi(u6.y);
            a4 += bflo(u6.z); a5 += bfhi(u6.z); a6 += bflo(u6.w); a7 += bfhi(u6.w);
            a0 += bflo(u7.x); a1 += bfhi(u7.x); a2 += bflo(u7.y); a3 += bfhi(u7.y);
            a4 += bflo(u7.z); a5 += bfhi(u7.z); a6 += bflo(u7.w); a7 += bfhi(u7.w);
        }
        float di = dinv[node];                  // (A^ h)_i = di * (sum + self)
        uint2 p0 = pack4(di * a0, di * a1, di * a2, di * a3);
        uint2 p1 = pack4(di * a4, di * a5, di * a6, di * a7);
        uint4 o; o.x = p0.x; o.y = p0.y; o.z = p1.x; o.w = p1.y;
        *(uint4*)(a_sh + nl * LDSW + sub * 8) = o;
    }
    __syncthreads();
    // MFMA phase: wave w -> cols w*32..+31, rows 0..15
    int w = tid >> 6, l = tid & 63;
    int lm = l & 15, lk = l >> 4;
    int cbase = w * 32;
    f32x4 acc[2];
    acc[0] = (f32x4)0.f; acc[1] = (f32x4)0.f;
#pragma unroll
    for (int kk = 0; kk < 4; kk++) {
        short8 af = *(const short8*)(a_sh + lm * LDSW + (kk * 4 + lk) * 8);
#pragma unroll
        for (int nt = 0; nt < 2; nt++) {
            short8 bf = *(const short8*)(Wt + (size_t)(cbase + nt * 16 + lm) * HID + (kk * 4 + lk) * 8);
            acc[nt] = __builtin_amdgcn_mfma_f32_16x16x32_bf16(bf, af, acc[nt], 0, 0, 0);
        }
    }
    int m = blockIdx.x * 16 + lm;
    float di = dinv[m];
    if (DOT == 0) {
#pragma unroll
        for (int nt = 0; nt < 2; nt++) {
            int n0 = cbase + nt * 16 + lk * 4;
            float4 b4 = *(const float4*)(bias + n0);
            float o0 = di * fmaxf(acc[nt][0] + b4.x, 0.f);
            float o1 = di * fmaxf(acc[nt][1] + b4.y, 0.f);
            float o2 = di * fmaxf(acc[nt][2] + b4.z, 0.f);
            float o3 = di * fmaxf(acc[nt][3] + b4.w, 0.f);
            *(uint2*)(hp_out + (size_t)m * HID + n0) = pack4(o0, o1, o2, o3);
        }
    } else {
        float s = 0.f;
#pragma unroll
        for (int nt = 0; nt < 2; nt++) {
            int n0 = cbase + nt * 16 + lk * 4;
            float4 b4 = *(const float4*)(bias + n0);
            float4 w4 = *(const float4*)(wtil + n0);
            s += di * fmaxf(acc[nt][0] + b4.x, 0.f) * w4.x
               + di * fmaxf(acc[nt][1] + b4.y, 0.f) * w4.y
               + di * fmaxf(acc[nt][2] + b4.z, 0.f) * w4.z
               + di * fmaxf(acc[nt][3] + b4.w, 0.f) * w4.w;
        }
        s += __shfl_xor(s, 16, 64);
        s += __shfl_xor(s, 32, 64);             // lanes with lk==0 hold row sum of 32 cols
        if (lk == 0) spart[w * 16 + lm] = s;
        __syncthreads();
        if (tid < 16)
            sp[blockIdx.x * 16 + tid] =
                spart[tid] + spart[16 + tid] + spart[32 + tid] + spart[48 + tid];
    }
}

// ---------------- graph head: scalar layer-3 agg + mean + sigmoid ----------------
__global__ __launch_bounds__(256) void gout_k(const float* __restrict__ sp,
                                              const int* __restrict__ goff,
                                              const int* __restrict__ deg,
                                              const unsigned short* __restrict__ csrc,
                                              const float* __restrict__ dinv,
                                              const float* __restrict__ cbuf,
                                              const float* __restrict__ lin_b,
                                              float* __restrict__ out) {
    int wave = (blockIdx.x * 256 + threadIdx.x) >> 6;   // one wave per graph
    int lane = threadIdx.x & 63;
    if (wave >= N_GRAPHS) return;
    int s0 = goff[wave], s1 = goff[wave + 1];
    float s = 0.f;
    for (int j = s0 + lane; j < s1; j += 64) {
        int d = deg[j];
        if (d > CAP) d = CAP;
        int ee = (d + 7) & ~7;
        if (ee > CAP) ee = CAP;
        const unsigned short* bk = csrc + ((size_t)j << CAPLOG);
        float acc = sp[j];                              // self
        for (int i = 0; i < ee; i += 4) {
            ushort4 r = *(const ushort4*)(bk + i);
            acc += sp[r.x] + sp[r.y] + sp[r.z] + sp[r.w];
        }
        s += dinv[j] * acc;
    }
#pragma unroll
    for (int o = 32; o >= 1; o >>= 1) s += __shfl_xor(s, o, 64);
    if (lane == 0) {
        int cnt = s1 - s0;
        float z = (cnt == 0) ? lin_b[0] : (s / (float)cnt + cbuf[0] + lin_b[0]);
        out[wave] = 1.0f / (1.0f + expf(-z));
    }
}

extern "C" void kernel_launch(void* const* d_in, const int* in_sizes, int n_in,
                              void* d_out, int out_size, void* d_ws, size_t ws_size,
                              hipStream_t stream) {
    const int* x      = (const int*)d_in[0];
    const int* ei     = (const int*)d_in[1];
    const int* batch  = (const int*)d_in[2];
    const float* emb  = (const float*)d_in[3];
    const float* W1   = (const float*)d_in[4];
    const float* b1   = (const float*)d_in[5];
    const float* W2   = (const float*)d_in[6];
    const float* b2   = (const float*)d_in[7];
    const float* W3   = (const float*)d_in[8];
    const float* b3   = (const float*)d_in[9];
    const float* lw   = (const float*)d_in[10];
    const float* lb   = (const float*)d_in[11];
    float* out = (float*)d_out;

    char* ws = (char*)d_ws;
    size_t off = 0;
    auto alloc = [&](size_t bytes) {
        void* p = ws + off;
        off = (off + bytes + 255) & ~(size_t)255;
        return p;
    };
    int*   cursor  = (int*)alloc((size_t)N_NODES * 4);          // becomes degree after fill
    float* dinv    = (float*)alloc((size_t)N_NODES * 4);
    unsigned short* csrc = (unsigned short*)alloc((size_t)N_NODES * CAP * 2);
    unsigned short* hpA  = (unsigned short*)alloc((size_t)(N_NODES + 1) * HID * 2);
    unsigned short* hpB  = (unsigned short*)alloc((size_t)(N_NODES + 1) * HID * 2);
    unsigned short* Wt   = (unsigned short*)alloc((size_t)2 * HID * HID * 2);
    float* wtil    = (float*)alloc((size_t)HID * 4);
    float* cbuf    = (float*)alloc(256);
    float* sp      = (float*)alloc((size_t)(N_NODES + 1) * 4);
    int*   goff    = (int*)alloc((size_t)(N_GRAPHS + 1) * 4);

    const int* row = ei;
    const int* col = ei + N_EDGES;

    init_k<<<NB_SCAN, 256, 0, stream>>>(cursor,
                                        (unsigned int*)(hpA + (size_t)SENTINEL * HID),
                                        (unsigned int*)(hpB + (size_t)SENTINEL * HID),
                                        sp);
    // partition-affine bucket fill (cursor doubles as degree counter) | weight prep
    mid_k<<<FB + PB, 256, 0, stream>>>(row, col, cursor, csrc,
                                       W1, W2, W3, b3, lw, batch,
                                       Wt, wtil, cbuf, goff);
    // atom encoder + dinv + sentinel padding (cursor == degree now)
    atomdinv_k<<<(N_NODES * 32) / 256, 256, 0, stream>>>(x, emb, cursor, dinv, csrc, hpA);

    // layer 1: fused gather + MFMA -> hpB
    fused_k<0><<<NBLK, 256, 0, stream>>>(hpA, Wt, b1, dinv, cursor, csrc, hpB, wtil, sp);
    // layer 2: fused gather + MFMA + dot(w~) -> sp directly (no hp write)
    fused_k<1><<<NBLK, 256, 0, stream>>>(hpB, Wt + 16384, b2, dinv, cursor, csrc, hpA, wtil, sp);

    // head: scalar layer-3 agg + mean + sigmoid
    gout_k<<<(N_GRAPHS * 64 + 255) / 256, 256, 0, stream>>>(sp, goff, cursor, csrc,
                                                            dinv, cbuf, lb, out);
}